// Round 1
// baseline (105.461 us; speedup 1.0000x reference)
//
#include <hip/hip_runtime.h>

// QuantumDMRGLayer: B=2048, L=196, M=16, NBL=10, pos_label=98 (fixed by setup).
// Round-8: the 128-wave chain_kernel was a serial latency wall (~1900 cyc/site
// vs ~150 cyc of issue work; <=1 wave/SIMD, zero TLP). The matrix chain is
// associative, so v8 splits each direction into 4 segments and computes
// per-sample 16x16 SEGMENT PRODUCTS in parallel: a wave runs the identical
// proven inner loop on 32 columns = 2 samples x 16 basis vectors.
//   seg_kernel: 8 segments x 1024 waves = 8192 waves (full TLP) -> throughput
//   bound: ~596k MFMAs ~ 8 us. Boundary matrices (16.8 MB) stored transposed
//   ([out][in]) so the combine reads are contiguous.
//   comb_out_kernel: per sample, v_left/v_right through 4 boundary matrices
//   each (16 shfl + 16 fma per apply), then the T contraction (fused, one
//   launch saved).
// prep_kernel / G-stream layout / per-site split-bf16 3-MFMA math unchanged
// from the verified round-7 kernel.

typedef __attribute__((ext_vector_type(8))) short short8;
typedef __attribute__((ext_vector_type(16))) float floatx16;

#define GSITE_DW 512                 // dwords per site (hi 256 | lo 256)
#define GDIR_DW (100 * GSITE_DW)     // 100 sites per dir (2-4 pad)
#define SEG_OFF_DW (2 * GDIR_DW)     // float offset of S in d_ws (102400)
// S: [8 segs][2048 samples][16 out][16 in] floats = 16.8 MB (ws use ~17.2 MB)

__device__ __forceinline__ unsigned bf16_rne(unsigned u) {
    return (u + 0x7FFFu + ((u >> 16) & 1u)) >> 16;
}

// ---- prep: build split-bf16, row-permuted G streams in d_ws (unchanged) ----
// lane l holds A-operand row r=l&31, k = 8*(l>>5)+j.  Stored value =
// G[pi(r), k],  pi = swap bits 2<->3 of low nibble (keeps bit4 = d).
//   left  (site p):    G[(d,nn),k] = AM[p,      d, k, nn]   (v <- v @ W)
//   right (site 193-p):G[(d,nn),k] = AM[193-p,  d, nn, k]   (v <- W @ v)
__global__ __launch_bounds__(256)
void prep_kernel(const float* __restrict__ AM, unsigned* __restrict__ WS)
{
    int t = blockIdx.x * 256 + threadIdx.x;    // < 51200
    const int w    = t & 3;  t >>= 2;          // dword pair index 0..3
    const int lane = t & 63; t >>= 6;
    const int p    = t % 100;
    const int dir  = t / 100;
    const int kb = (lane >> 5) << 3;
    const int r  = lane & 31;
    const int rr = (r & 0x13) | ((r & 4) << 1) | ((r & 8) >> 1);  // pi(r)
    const int d = rr >> 4, nn = rr & 15;
    const int lim = dir ? 96 : 98;
    const int a = dir ? (193 - p) : p;
    const int k0 = kb + 2 * w;
    float g0 = 0.f, g1 = 0.f;
    if (p < lim) {
        const float* Ab = AM + a * 512 + d * 256;
        if (dir == 0) { g0 = Ab[k0 * 16 + nn]; g1 = Ab[(k0 + 1) * 16 + nn]; }
        else          { g0 = Ab[nn * 16 + k0]; g1 = Ab[nn * 16 + k0 + 1]; }
    }
    const unsigned u0 = __float_as_uint(g0), u1 = __float_as_uint(g1);
    const unsigned h0 = bf16_rne(u0), h1 = bf16_rne(u1);
    const float l0f = g0 - __uint_as_float(h0 << 16);
    const float l1f = g1 - __uint_as_float(h1 << 16);
    const unsigned lo0 = bf16_rne(__float_as_uint(l0f));
    const unsigned lo1 = bf16_rne(__float_as_uint(l1f));
    unsigned* gp = WS + (dir * 100 + p) * GSITE_DW;
    gp[lane * 4 + w]       = (h1 << 16) | h0;
    gp[256 + lane * 4 + w] = (lo1 << 16) | lo0;
}

// ---- stage 1: per-sample segment products via basis-vector chains ----
// wave = (segment 0..7, sample-pair 0..1023); columns = 2 samples x 16 basis.
// dir0 segment [p0,p1): col m accumulates e_m^T W_p0...W_{p1-1} = row m of P.
// dir1 segment [p0,p1): col m accumulates W_{193-(p1-1)}..W_{193-p0} e_m
//                       = column m of Q.
// Both store S[seg][s][out k][in m] so the combine is v'[n]=sum_m S[n][m]v[m].
__global__ __launch_bounds__(256, 4)
void seg_kernel(const float* __restrict__ X,
                const unsigned* __restrict__ WS,
                float* __restrict__ S)
{
    const int lane = threadIdx.x & 63;
    const int gw   = blockIdx.x * 4 + (threadIdx.x >> 6); // 0..8191
    const int seg  = gw >> 10;                 // 0..7
    const int pair = gw & 1023;
    const int dir  = seg >> 2;
    const int si   = seg & 3;
    // dir0: 98 = 25+25+24+24 ; dir1: 96 = 24*4
    int p0, p1;
    if (dir == 0) { p0 = (si < 2) ? 25 * si : 50 + 24 * (si - 2);
                    p1 = p0 + ((si < 2) ? 25 : 24); }
    else          { p0 = 24 * si; p1 = p0 + 24; }

    const int m  = lane & 15;                  // basis index (column)
    const int s  = pair * 2 + ((lane >> 4) & 1);
    const int kb = (lane >> 5) << 3;           // this lane's k-half base
    const float* Xs = X + s * 392;
    const unsigned* Gb = WS + dir * GDIR_DW + lane * 4;

    float w[8];
    int4 vh4, vl4;
    auto pack = [&]() {
#pragma unroll
        for (int q = 0; q < 4; ++q) {
            const unsigned u0 = __float_as_uint(w[2 * q]);
            const unsigned u1 = __float_as_uint(w[2 * q + 1]);
            const unsigned h0 = u0 & 0xFFFF0000u, h1 = u1 & 0xFFFF0000u;
            const float l0 = w[2 * q]     - __uint_as_float(h0);
            const float l1 = w[2 * q + 1] - __uint_as_float(h1);
            ((unsigned*)&vh4)[q] = h1 | (h0 >> 16);
            ((unsigned*)&vl4)[q] = (__float_as_uint(l1) & 0xFFFF0000u) |
                                   (__float_as_uint(l0) >> 16);
        }
    };

    // ---- init: basis vector e_m (exact in bf16, lo = 0) ----
#pragma unroll
    for (int j = 0; j < 8; ++j)
        w[j] = (kb + j == m) ? 1.0f : 0.0f;
    pack();

    // ---- 4-site register ring (same as verified chain loop) ----
    int4 GH[4], GL[4];
    float2 xr[4];
#pragma unroll
    for (int i = 0; i < 4; ++i) {
        const int p = p0 + i;                  // seg length >= 24, in-range
        GH[i] = *(const int4*)(Gb + p * GSITE_DW);
        GL[i] = *(const int4*)(Gb + p * GSITE_DW + 256);
        xr[i] = *(const float2*)(Xs + (dir ? (388 - 2 * p) : (2 + 2 * p)));
    }

    for (int c = 0; c < 7; ++c) {              // 28 slots >= 25 sites
#pragma unroll
        for (int j4 = 0; j4 < 4; ++j4) {
            const int p = p0 + 4 * c + j4;
            if (p < p1) {
                const short8 ah = *(short8*)&GH[j4];
                const short8 al = *(short8*)&GL[j4];
                const short8 bh = *(short8*)&vh4;
                const short8 bl = *(short8*)&vl4;
                floatx16 D = {};
                D = __builtin_amdgcn_mfma_f32_32x32x16_bf16(ah, bh, D, 0, 0, 0);
                D = __builtin_amdgcn_mfma_f32_32x32x16_bf16(ah, bl, D, 0, 0, 0);
                D = __builtin_amdgcn_mfma_f32_32x32x16_bf16(al, bh, D, 0, 0, 0);
                const float2 xs = xr[j4];
#pragma unroll
                for (int j = 0; j < 8; ++j)    // D[j]=W0, D[j+8]=W1, k=kb+j
                    w[j] = fmaf(xs.x, D[j], xs.y * D[j + 8]);
                pack();
            }
            int pn = p + 4;                    // prefetch into this slot
            if (pn >= p1) pn = 99;             // pad site (zeroed by prep)
            GH[j4] = *(const int4*)(Gb + pn * GSITE_DW);
            GL[j4] = *(const int4*)(Gb + pn * GSITE_DW + 256);
            xr[j4] = *(const float2*)(Xs + (dir ? (388 - 2 * pn) : (2 + 2 * pn)));
        }
    }

    // ---- store segment product, transposed to [out k][in m] ----
    float* Sp = S + ((seg * 2048 + s) << 8) + m;
#pragma unroll
    for (int j = 0; j < 8; ++j)
        Sp[(kb + j) << 4] = w[j];
}

// ---- stage 2 + epilogue: combine boundary matrices, contract with T ----
// block = 8 samples x 2 chains x 16 components. Per thread: 4 matrix applies
// (16 shfl + 16 fma each, rows contiguous), states to LDS, then 80 threads
// do out[s,l] = sum_{m,n} L[m] T[m,n,l] R[n].
__global__ __launch_bounds__(256)
void comb_out_kernel(const float* __restrict__ X,
                     const float* __restrict__ AL,
                     const float* __restrict__ AR,
                     const float* __restrict__ T,
                     const float* __restrict__ S,
                     float* __restrict__ OUT)
{
    __shared__ float sT[2560];
    __shared__ float sst[8][2][16];
    const int tid = threadIdx.x;
    for (int k = tid; k < 640; k += 256)
        ((float4*)sT)[k] = ((const float4*)T)[k];

    const int sl    = tid >> 5;          // 0..7
    const int chain = (tid >> 4) & 1;    // 0 = left, 1 = right
    const int n     = tid & 15;
    const int s     = blockIdx.x * 8 + sl;
    const float* Xs = X + s * 392;

    float v;
    if (chain == 0) {
        const float2 x = *(const float2*)(Xs);
        v = x.x * AL[n] + x.y * AL[16 + n];
    } else {
        const float2 x = *(const float2*)(Xs + 390);
        v = x.x * AR[n] + x.y * AR[16 + n];
    }

#pragma unroll
    for (int q = 0; q < 4; ++q) {
        const int seg = chain * 4 + q;
        const float4* Ps =
            (const float4*)(S + ((seg * 2048 + s) << 8) + (n << 4));
        const float4 a = Ps[0], b = Ps[1], c = Ps[2], d = Ps[3];
        float t0 =      a.x * __shfl(v,  0, 16);
        t0 = fmaf(a.y, __shfl(v,  1, 16), t0);
        t0 = fmaf(a.z, __shfl(v,  2, 16), t0);
        t0 = fmaf(a.w, __shfl(v,  3, 16), t0);
        float t1 =      b.x * __shfl(v,  4, 16);
        t1 = fmaf(b.y, __shfl(v,  5, 16), t1);
        t1 = fmaf(b.z, __shfl(v,  6, 16), t1);
        t1 = fmaf(b.w, __shfl(v,  7, 16), t1);
        float t2 =      c.x * __shfl(v,  8, 16);
        t2 = fmaf(c.y, __shfl(v,  9, 16), t2);
        t2 = fmaf(c.z, __shfl(v, 10, 16), t2);
        t2 = fmaf(c.w, __shfl(v, 11, 16), t2);
        float t3 =      d.x * __shfl(v, 12, 16);
        t3 = fmaf(d.y, __shfl(v, 13, 16), t3);
        t3 = fmaf(d.z, __shfl(v, 14, 16), t3);
        t3 = fmaf(d.w, __shfl(v, 15, 16), t3);
        v = (t0 + t1) + (t2 + t3);
    }
    sst[sl][chain][n] = v;
    __syncthreads();

    if (tid < 80) {
        const int s2 = tid / 10, l = tid - s2 * 10;
        const float* L = sst[s2][0];
        const float4 Ra = *(const float4*)&sst[s2][1][0];
        const float4 Rb = *(const float4*)&sst[s2][1][4];
        const float4 Rc = *(const float4*)&sst[s2][1][8];
        const float4 Rd = *(const float4*)&sst[s2][1][12];
        float acc = 0.f;
#pragma unroll
        for (int m = 0; m < 16; ++m) {
            const float lm = L[m];
            const float* Tp = sT + m * 160 + l;
            acc = fmaf(lm * Ra.x, Tp[0],   acc);
            acc = fmaf(lm * Ra.y, Tp[10],  acc);
            acc = fmaf(lm * Ra.z, Tp[20],  acc);
            acc = fmaf(lm * Ra.w, Tp[30],  acc);
            acc = fmaf(lm * Rb.x, Tp[40],  acc);
            acc = fmaf(lm * Rb.y, Tp[50],  acc);
            acc = fmaf(lm * Rb.z, Tp[60],  acc);
            acc = fmaf(lm * Rb.w, Tp[70],  acc);
            acc = fmaf(lm * Rc.x, Tp[80],  acc);
            acc = fmaf(lm * Rc.y, Tp[90],  acc);
            acc = fmaf(lm * Rc.z, Tp[100], acc);
            acc = fmaf(lm * Rc.w, Tp[110], acc);
            acc = fmaf(lm * Rd.x, Tp[120], acc);
            acc = fmaf(lm * Rd.y, Tp[130], acc);
            acc = fmaf(lm * Rd.z, Tp[140], acc);
            acc = fmaf(lm * Rd.w, Tp[150], acc);
        }
        OUT[(blockIdx.x * 8 + s2) * 10 + l] = acc;
    }
}

extern "C" void kernel_launch(void* const* d_in, const int* in_sizes, int n_in,
                              void* d_out, int out_size, void* d_ws, size_t ws_size,
                              hipStream_t stream)
{
    const float* X  = (const float*)d_in[0];   // (2048,196,2)
    const float* AL = (const float*)d_in[1];   // (2,16)
    const float* AM = (const float*)d_in[2];   // (194,2,16,16)
    const float* AR = (const float*)d_in[3];   // (2,16)
    const float* T  = (const float*)d_in[4];   // (16,16,10)
    (void)in_sizes; (void)n_in; (void)out_size; (void)ws_size;
    unsigned* WS = (unsigned*)d_ws;            // G streams: 400 KB
    float* S     = (float*)d_ws + SEG_OFF_DW;  // segment products: 16.8 MB
    float* OUT   = (float*)d_out;              // (2048,10)

    hipLaunchKernelGGL(prep_kernel,     dim3(200),  dim3(256), 0, stream, AM, WS);
    hipLaunchKernelGGL(seg_kernel,      dim3(2048), dim3(256), 0, stream, X, WS, S);
    hipLaunchKernelGGL(comb_out_kernel, dim3(256),  dim3(256), 0, stream,
                       X, AL, AR, T, S, OUT);
}

// Round 2
// 94.396 us; speedup vs baseline: 1.1172x; 1.1172x over previous
//
#include <hip/hip_runtime.h>

// QuantumDMRGLayer: B=2048, L=196, M=16, NBL=10, pos_label=98 (fixed by setup).
// Round-9: round-8's segment split was right about parallelism but wrong about
// the combine: a 16.8MB global S round-trip + a 1-wave/SIMD comb kernel + 3
// serialized launches ate the gain (87 -> 105us). v9 fuses everything past
// prep into ONE kernel:
//   - block = 4 samples, 8 waves; wave w owns segment w (dir = w>>2, 4 segs
//     per direction) and runs the proven split-bf16 3-MFMA chain on
//     2 independent 32-column chains (2x2 samples x 16 basis vectors) per
//     G-load -> halves G traffic, doubles in-wave ILP.
//   - segment products go to LDS (sS[8][4][16][17], pad-17 = conflict-free
//     tail reads); after one __syncthreads, waves 0-1 do the boundary
//     combine (shfl within 16-lane groups) and the T contraction in-block.
//   - bf16 split-pack via v_perm_b32 (6 ops / 2 values vs ~9).
// No S buffer (ws back to 400KB), no third kernel, no scatter stores.
// prep_kernel / G-stream layout / per-site numerics unchanged (verified).

typedef __attribute__((ext_vector_type(8))) short short8;
typedef __attribute__((ext_vector_type(16))) float floatx16;

#define GSITE_DW 512                 // dwords per site (hi 256 | lo 256)
#define GDIR_DW (100 * GSITE_DW)     // 100 sites per dir (2-4 pad)

__device__ __forceinline__ unsigned bf16_rne(unsigned u) {
    return (u + 0x7FFFu + ((u >> 16) & 1u)) >> 16;
}

// ---- prep: build split-bf16, row-permuted G streams in d_ws (unchanged) ----
// lane l holds A-operand row r=l&31, k = 8*(l>>5)+j.  Stored value =
// G[pi(r), k],  pi = swap bits 2<->3 of low nibble (keeps bit4 = d).
//   left  (site p):    G[(d,nn),k] = AM[p,      d, k, nn]   (v <- v @ W)
//   right (site 193-p):G[(d,nn),k] = AM[193-p,  d, nn, k]   (v <- W @ v)
__global__ __launch_bounds__(256)
void prep_kernel(const float* __restrict__ AM, unsigned* __restrict__ WS)
{
    int t = blockIdx.x * 256 + threadIdx.x;    // < 51200
    const int w    = t & 3;  t >>= 2;          // dword index 0..3
    const int lane = t & 63; t >>= 6;
    const int p    = t % 100;
    const int dir  = t / 100;
    const int kb = (lane >> 5) << 3;
    const int r  = lane & 31;
    const int rr = (r & 0x13) | ((r & 4) << 1) | ((r & 8) >> 1);  // pi(r)
    const int d = rr >> 4, nn = rr & 15;
    const int lim = dir ? 96 : 98;
    const int a = dir ? (193 - p) : p;
    const int k0 = kb + 2 * w;
    float g0 = 0.f, g1 = 0.f;
    if (p < lim) {
        const float* Ab = AM + a * 512 + d * 256;
        if (dir == 0) { g0 = Ab[k0 * 16 + nn]; g1 = Ab[(k0 + 1) * 16 + nn]; }
        else          { g0 = Ab[nn * 16 + k0]; g1 = Ab[nn * 16 + k0 + 1]; }
    }
    const unsigned u0 = __float_as_uint(g0), u1 = __float_as_uint(g1);
    const unsigned h0 = bf16_rne(u0), h1 = bf16_rne(u1);
    const float l0f = g0 - __uint_as_float(h0 << 16);
    const float l1f = g1 - __uint_as_float(h1 << 16);
    const unsigned lo0 = bf16_rne(__float_as_uint(l0f));
    const unsigned lo1 = bf16_rne(__float_as_uint(l1f));
    unsigned* gp = WS + (dir * 100 + p) * GSITE_DW;
    gp[lane * 4 + w]       = (h1 << 16) | h0;
    gp[256 + lane * 4 + w] = (lo1 << 16) | lo0;
}

// ---- fused: segment chains -> LDS -> combine -> T contraction ----
// wave wv (0..7): dir = wv>>2, si = wv&3.
//   dir0: 98 = 25+25+24+24 ; dir1: 96 = 24*4.
// Chain 0 = samples sb+{0,1}, chain 1 = samples sb+{2,3} (16 basis cols each).
// sS[seg][smp][out k][in m] (pad 17) so apply is v'[n] = sum_m S[n][m] v[m].
__global__ __launch_bounds__(512, 4)
void fused_kernel(const float* __restrict__ X,
                  const float* __restrict__ AL,
                  const float* __restrict__ AR,
                  const float* __restrict__ T,
                  const unsigned* __restrict__ WS,
                  float* __restrict__ OUT)
{
    __shared__ float sT[2560];
    __shared__ float sS[8][4][16][17];
    __shared__ float sv[4][2][16];

    const int tid  = threadIdx.x;
    const int lane = tid & 63;
    const int wv   = tid >> 6;                 // 0..7 = segment
    for (int k = tid; k < 640; k += 512)
        ((float4*)sT)[k] = ((const float4*)T)[k];

    const int dir = wv >> 2;
    const int si  = wv & 3;
    int p0, p1;
    if (dir == 0) { p0 = (si < 2) ? 25 * si : 50 + 24 * (si - 2);
                    p1 = p0 + ((si < 2) ? 25 : 24); }
    else          { p0 = 24 * si; p1 = p0 + 24; }

    const int sel = (lane >> 4) & 1;           // sample within chain pair
    const int m   = lane & 15;                 // basis index (column)
    const int kb  = (lane >> 5) << 3;          // this lane's k-half base
    const int sb  = blockIdx.x * 4;
    const float* Xs0 = X + (sb + sel) * 392;
    const float* Xs1 = X + (sb + 2 + sel) * 392;
    const unsigned* Gb = WS + dir * GDIR_DW + lane * 4;

    // ---- chain state: fp32 shadow + packed bf16 hi/lo fragments ----
    float w0[8], w1[8];
    int4 vh0, vl0, vh1, vl1;
#pragma unroll
    for (int j = 0; j < 8; ++j) w0[j] = (kb + j == m) ? 1.0f : 0.0f;
#pragma unroll
    for (int q = 0; q < 4; ++q) {              // basis exact in bf16, lo = 0
        const unsigned h0 = __float_as_uint(w0[2 * q]) & 0xFFFF0000u;
        const unsigned h1 = __float_as_uint(w0[2 * q + 1]) & 0xFFFF0000u;
        ((unsigned*)&vh0)[q] = h1 | (h0 >> 16);
        ((unsigned*)&vl0)[q] = 0;
        w1[2 * q] = w0[2 * q]; w1[2 * q + 1] = w0[2 * q + 1];
    }
    vh1 = vh0; vl1 = vl0;

    // combine D -> fp32 state + split-bf16 repack (v_perm packing)
    auto comb = [&](const floatx16& D, const float2 xs,
                    float* wq, int4& vh, int4& vl) {
#pragma unroll
        for (int q = 0; q < 4; ++q) {
            const float a0 = fmaf(xs.x, D[2 * q],     xs.y * D[2 * q + 8]);
            const float a1 = fmaf(xs.x, D[2 * q + 1], xs.y * D[2 * q + 9]);
            wq[2 * q] = a0; wq[2 * q + 1] = a1;
            const unsigned u0 = __float_as_uint(a0);
            const unsigned u1 = __float_as_uint(a1);
            const float l0 = a0 - __uint_as_float(u0 & 0xFFFF0000u);
            const float l1 = a1 - __uint_as_float(u1 & 0xFFFF0000u);
            ((unsigned*)&vh)[q] = __builtin_amdgcn_perm(u1, u0, 0x07060302u);
            ((unsigned*)&vl)[q] = __builtin_amdgcn_perm(
                __float_as_uint(l1), __float_as_uint(l0), 0x07060302u);
        }
    };

    // ---- 2-site register ring ----
    int4 GH[2], GL[2];
    float2 xr0[2], xr1[2];
#pragma unroll
    for (int i = 0; i < 2; ++i) {
        const int p = p0 + i;                  // seg length >= 24, in-range
        GH[i] = *(const int4*)(Gb + p * GSITE_DW);
        GL[i] = *(const int4*)(Gb + p * GSITE_DW + 256);
        const int xo = dir ? (388 - 2 * p) : (2 + 2 * p);
        xr0[i] = *(const float2*)(Xs0 + xo);
        xr1[i] = *(const float2*)(Xs1 + xo);
    }

    for (int c = 0; c < 14; ++c) {             // 28 slots >= 25 sites
#pragma unroll
        for (int j2 = 0; j2 < 2; ++j2) {
            const int p = p0 + 2 * c + j2;
            if (p < p1) {
                const short8 ah  = *(const short8*)&GH[j2];
                const short8 al  = *(const short8*)&GL[j2];
                const short8 bh0 = *(const short8*)&vh0;
                const short8 bl0 = *(const short8*)&vl0;
                floatx16 D0 = {};
                D0 = __builtin_amdgcn_mfma_f32_32x32x16_bf16(ah, bh0, D0, 0, 0, 0);
                D0 = __builtin_amdgcn_mfma_f32_32x32x16_bf16(ah, bl0, D0, 0, 0, 0);
                D0 = __builtin_amdgcn_mfma_f32_32x32x16_bf16(al, bh0, D0, 0, 0, 0);
                comb(D0, xr0[j2], w0, vh0, vl0);
                const short8 bh1 = *(const short8*)&vh1;
                const short8 bl1 = *(const short8*)&vl1;
                floatx16 D1 = {};
                D1 = __builtin_amdgcn_mfma_f32_32x32x16_bf16(ah, bh1, D1, 0, 0, 0);
                D1 = __builtin_amdgcn_mfma_f32_32x32x16_bf16(ah, bl1, D1, 0, 0, 0);
                D1 = __builtin_amdgcn_mfma_f32_32x32x16_bf16(al, bh1, D1, 0, 0, 0);
                comb(D1, xr1[j2], w1, vh1, vl1);
            }
            int pn = p + 2;                    // prefetch into this slot
            if (pn >= p1) pn = 99;             // pad site (zeroed by prep)
            GH[j2] = *(const int4*)(Gb + pn * GSITE_DW);
            GL[j2] = *(const int4*)(Gb + pn * GSITE_DW + 256);
            const int xo = dir ? (388 - 2 * pn) : (2 + 2 * pn);
            xr0[j2] = *(const float2*)(Xs0 + xo);
            xr1[j2] = *(const float2*)(Xs1 + xo);
        }
    }

    // ---- segment products to LDS: sS[seg][smp][k][m] ----
#pragma unroll
    for (int j = 0; j < 8; ++j) {
        sS[wv][sel][kb + j][m]     = w0[j];
        sS[wv][2 + sel][kb + j][m] = w1[j];
    }
    __syncthreads();

    // ---- combine + T contraction (waves 0-1: 4 samples x 2 chains x 16) ----
    if (wv < 2) {
        const int smp   = wv * 2 + (lane >> 5);    // 0..3
        const int chain = (lane >> 4) & 1;         // 0 = left, 1 = right
        const int n     = lane & 15;
        const float2 x  = *(const float2*)(X + (sb + smp) * 392 +
                                           (chain ? 390 : 0));
        const float* Ab = chain ? AR : AL;
        float v = x.x * Ab[n] + x.y * Ab[16 + n];
#pragma unroll
        for (int q = 0; q < 4; ++q) {
            const float* Srow = &sS[chain * 4 + q][smp][n][0];
            float acc = 0.f;
#pragma unroll
            for (int mm = 0; mm < 16; ++mm)
                acc = fmaf(Srow[mm], __shfl(v, mm, 16), acc);
            v = acc;
        }
        sv[smp][chain][n] = v;                 // same-wave LDS, lockstep-safe

        if (lane < 20) {
            const int s2 = lane / 10, l = lane - s2 * 10;
            const int sm = wv * 2 + s2;
            const float* Lp = sv[sm][0];
            const float* Rp = sv[sm][1];
            float acc = 0.f;
#pragma unroll
            for (int mm = 0; mm < 16; ++mm) {
                const float lm = Lp[mm];
                const float* Tp = sT + mm * 160 + l;
#pragma unroll
                for (int nn = 0; nn < 16; ++nn)
                    acc = fmaf(lm * Rp[nn], Tp[nn * 10], acc);
            }
            OUT[(sb + sm) * 10 + l] = acc;
        }
    }
}

extern "C" void kernel_launch(void* const* d_in, const int* in_sizes, int n_in,
                              void* d_out, int out_size, void* d_ws, size_t ws_size,
                              hipStream_t stream)
{
    const float* X  = (const float*)d_in[0];   // (2048,196,2)
    const float* AL = (const float*)d_in[1];   // (2,16)
    const float* AM = (const float*)d_in[2];   // (194,2,16,16)
    const float* AR = (const float*)d_in[3];   // (2,16)
    const float* T  = (const float*)d_in[4];   // (16,16,10)
    (void)in_sizes; (void)n_in; (void)out_size; (void)ws_size;
    unsigned* WS = (unsigned*)d_ws;            // G streams: 400 KB
    float* OUT   = (float*)d_out;              // (2048,10)

    hipLaunchKernelGGL(prep_kernel,  dim3(200), dim3(256), 0, stream, AM, WS);
    hipLaunchKernelGGL(fused_kernel, dim3(512), dim3(512), 0, stream,
                       X, AL, AR, T, WS, OUT);
}